// Round 10
// baseline (3820.207 us; speedup 1.0000x reference)
//
#include <hip/hip_runtime.h>
#include <stdint.h>

// Problem constants: B=2048, S=512, F=64, H=256
#define SEQ   512
#define FD    64
#define HD    256
#define ZSTR  324            // bf16 elems per Z row; 162 words % 8 == 2 (conflict-free b128, <=2-way scalar writes)
#define CSTR  260            // 130 words % 8 == 2

// ws layout (prep writes, main reads): 8 wave-roles w (two 16-col j-slices each).
// Per role: 16 groups (p=i>>3, h=(i>>2)&1, nt=i&3) x 5 chunks x 1KB, consumption order.
// Chunk = 64 lanes x 16B, exact B-fragment order: lane l holds
//   W[n = nt*256 + (2w+p)*16 + (l&15)][k = h*160 + c*32 + (l>>4)*8 + e], e=0..7.
// Dense W at DENSE_OFF: 4 roles x 8 chunks x 1KB.
#define GRPB      5120
#define WGB       (16 * GRPB)        // 81,920 B per wave-role
#define DENSE_OFF (8 * WGB)          // 655,360 B

typedef __attribute__((ext_vector_type(8))) __bf16 bf16x8;
typedef __attribute__((ext_vector_type(4))) float  f32x4;

__device__ __forceinline__ float sigm(float x) {
    return __builtin_amdgcn_rcpf(1.0f + __expf(-x));
}
__device__ __forceinline__ float tanh_(float x) {
    return 2.0f * __builtin_amdgcn_rcpf(1.0f + __expf(-2.0f * x)) - 1.0f;
}

// ---------------- prep: fp32 weights -> bf16 fragment chunks in ws ----------------
__global__ __launch_bounds__(64) void prep_weights(
    const float* __restrict__ W_ih, const float* __restrict__ W_hh,
    const float* __restrict__ W_dense, __bf16* __restrict__ wsb)
{
    const int b = blockIdx.x, l = threadIdx.x, lr = l & 15, lg = l >> 4;
    if (b < 128) {
        const int w = b >> 4, i = b & 15;
        const int s = 2 * w + (i >> 3), h = (i >> 2) & 1, nt = i & 3;
        const int n = nt * 256 + s * 16 + lr;
        for (int c = 0; c < 5; ++c) {
            const int k0 = h * 160 + c * 32 + lg * 8;
            const float* src = (k0 < 64) ? (W_ih + n * 64 + k0)
                                         : (W_hh + n * 256 + (k0 - 64));
            bf16x8 v;
            for (int e = 0; e < 8; ++e) v[e] = (__bf16)src[e];
            *(bf16x8*)(wsb + (size_t)((w * 16 + i) * 5 + c) * 512 + l * 8) = v;
        }
    } else {
        const int d = b - 128;          // dense role 0..3
        const int f = d * 16 + lr;
        for (int c = 0; c < 8; ++c) {
            const float* src = W_dense + f * 256 + c * 32 + lg * 8;
            bf16x8 v;
            for (int e = 0; e < 8; ++e) v[e] = (__bf16)src[e];
            *(bf16x8*)(wsb + DENSE_OFF / 2 + d * 4096 + c * 512 + l * 8) = v;
        }
    }
}

// ---------------- main persistent LSTM kernel ----------------
// 128 blocks x 512 threads (8 waves). waves_per_eu(2,2) -> 128 arch-VGPR budget
// (the ONE config that reliably produced 128 across R3-R6; R9's launch_bounds(1024,4)
// gave 52 and the allocator sank the prefetches). Each wave owns two 16-col j-slices,
// streams ALL 16 weight groups L2 -> VGPR with a 2-group register double-buffer.
// No resident weight class (remat, R3-R6), no LDS weight staging (LDS-BW, R8),
// no manual vmcnt (spill-corruption class, R7). Live set ~107 < 128.
__global__ __launch_bounds__(512) __attribute__((amdgpu_waves_per_eu(2, 2)))
void lstm_persist(
    const float* __restrict__ h0, const float* __restrict__ c0,
    const float* __restrict__ b_ih, const float* __restrict__ b_hh,
    const float* __restrict__ b_dense, const __bf16* __restrict__ wsb,
    float* __restrict__ out)
{
    __shared__ __align__(16) __bf16 Zb[2 * 16 * ZSTR];   // 20,736 B
    __shared__ __align__(16) __bf16 CBb[16 * CSTR];      //  8,320 B

    const int tid = threadIdx.x;
    const int w   = tid >> 6;       // wave 0..7: j-slices {2w, 2w+1}
    const int l   = tid & 63;
    const int lr  = l & 15;
    const int lg  = l >> 4;
    const int row0 = blockIdx.x * 16;

    const __bf16* wgbase = wsb + (size_t)w * (WGB / 2);              // this wave's 16 groups
    const __bf16* wdbase = wsb + DENSE_OFF / 2 + w * 4096 + l * 8;   // dense chunks (w<4)

    // ---- biases, initial state (two slices per wave) ----
    float biasv[2][4];
    float creg[2][4];
#pragma unroll
    for (int p = 0; p < 2; ++p) {
        const int jj = (2 * w + p) * 16 + lr;
#pragma unroll
        for (int nt = 0; nt < 4; ++nt) {
            const int n = nt * 256 + jj;
            biasv[p][nt] = b_ih[n] + b_hh[n];
        }
#pragma unroll
        for (int r = 0; r < 4; ++r)
            creg[p][r] = c0[(size_t)(row0 + lg * 4 + r) * HD + jj];
    }
    float ybias = (w < 4) ? b_dense[w * 16 + lr] : 0.0f;

    // ---- stage h0 into Z0 h-part (512 threads x 8 elems) ----
    {
        const int e0 = tid * 8;
        const int m  = e0 >> 8;
        const int j8 = e0 & 255;
        const float4 h1 = *(const float4*)(h0 + (size_t)(row0 + m) * HD + j8);
        const float4 h2 = *(const float4*)(h0 + (size_t)(row0 + m) * HD + j8 + 4);
        __bf16* zp = &Zb[m * ZSTR + 64 + j8];
        zp[0] = (__bf16)h1.x; zp[1] = (__bf16)h1.y; zp[2] = (__bf16)h1.z; zp[3] = (__bf16)h1.w;
        zp[4] = (__bf16)h2.x; zp[5] = (__bf16)h2.y; zp[6] = (__bf16)h2.z; zp[7] = (__bf16)h2.w;
    }
    __syncthreads();

    // ---- x_0 = dense(h0) -> Z0 x-part ----
    if (w < 4) {
        f32x4 ya = {ybias, ybias, ybias, ybias};
#pragma unroll
        for (int c = 0; c < 8; ++c) {
            bf16x8 wdc = *(const bf16x8*)(wdbase + c * 512);
            bf16x8 av  = *(const bf16x8*)(&Zb[lr * ZSTR + 64 + c * 32 + lg * 8]);
            ya = __builtin_amdgcn_mfma_f32_16x16x32_bf16(av, wdc, ya, 0, 0, 0);
        }
#pragma unroll
        for (int r = 0; r < 4; ++r)
            Zb[(lg * 4 + r) * ZSTR + w * 16 + lr] = (__bf16)ya[r];
    }

    float* outp = out + (size_t)row0 * SEQ * FD;

    // ---------------- 512-step recurrence ----------------
    for (int t = 0; t < SEQ; ++t) {
        __syncthreads();   // barrier A: Z[cur] (h + x) complete

        const __bf16* Zc = Zb + (t & 1) * (16 * ZSTR);
        __bf16*       Zn = Zb + ((t + 1) & 1) * (16 * ZSTR);

        // per-lane marching pointer over this wave's 80 chunks; laundered per step so
        // LICM can't hoist the (t-invariant) weight loads out of the t-loop.
        const __bf16* gp = wgbase + l * 8;
        asm volatile("" : "+v"(gp));

        // register double-buffer: group i even -> sA, odd -> sB
        bf16x8 sA[5], sB[5];
#pragma unroll
        for (int c = 0; c < 5; ++c) sA[c] = *(const bf16x8*)(gp + c * 512);
#pragma unroll
        for (int c = 0; c < 5; ++c) sB[c] = *(const bf16x8*)(gp + 2560 + c * 512);

        bf16x8 aph[5];     // A-frags for the current k-half only
        f32x4  acc[4];

#pragma unroll
        for (int i = 0; i < 16; ++i) {
            const int p = i >> 3, h = (i >> 2) & 1, nt = i & 3;

            // phase start: (re)load the 5 A-frags for this k-half
            if ((i & 3) == 0) {
#pragma unroll
                for (int c = 0; c < 5; ++c)
                    aph[c] = *(const bf16x8*)(&Zc[lr * ZSTR + (h * 5 + c) * 32 + lg * 8]);
            }

            const float bb = biasv[p][nt];
            f32x4 cc = (h == 0) ? f32x4{bb, bb, bb, bb} : acc[nt];
            if ((i & 1) == 0) {
                cc = __builtin_amdgcn_mfma_f32_16x16x32_bf16(aph[0], sA[0], cc, 0, 0, 0);
                cc = __builtin_amdgcn_mfma_f32_16x16x32_bf16(aph[1], sA[1], cc, 0, 0, 0);
                cc = __builtin_amdgcn_mfma_f32_16x16x32_bf16(aph[2], sA[2], cc, 0, 0, 0);
                cc = __builtin_amdgcn_mfma_f32_16x16x32_bf16(aph[3], sA[3], cc, 0, 0, 0);
                cc = __builtin_amdgcn_mfma_f32_16x16x32_bf16(aph[4], sA[4], cc, 0, 0, 0);
                if (i + 2 < 16) {     // prefetch group i+2 into the buffer just freed
#pragma unroll
                    for (int c = 0; c < 5; ++c)
                        sA[c] = *(const bf16x8*)(gp + (i + 2) * 2560 + c * 512);
                }
            } else {
                cc = __builtin_amdgcn_mfma_f32_16x16x32_bf16(aph[0], sB[0], cc, 0, 0, 0);
                cc = __builtin_amdgcn_mfma_f32_16x16x32_bf16(aph[1], sB[1], cc, 0, 0, 0);
                cc = __builtin_amdgcn_mfma_f32_16x16x32_bf16(aph[2], sB[2], cc, 0, 0, 0);
                cc = __builtin_amdgcn_mfma_f32_16x16x32_bf16(aph[3], sB[3], cc, 0, 0, 0);
                cc = __builtin_amdgcn_mfma_f32_16x16x32_bf16(aph[4], sB[4], cc, 0, 0, 0);
                if (i + 2 < 16) {
#pragma unroll
                    for (int c = 0; c < 5; ++c)
                        sB[c] = *(const bf16x8*)(gp + (i + 2) * 2560 + c * 512);
                }
            }
            acc[nt] = cc;

            if ((i & 7) == 7) {
                // element-wise LSTM update for slice p (gates i,f,g,o complete)
                const int jj = (2 * w + p) * 16 + lr;
#pragma unroll
                for (int r = 0; r < 4; ++r) {
                    const int m = lg * 4 + r;
                    const float ig = sigm(acc[0][r]);
                    const float fg = sigm(acc[1][r]);
                    const float gg = tanh_(acc[2][r]);
                    const float og = sigm(acc[3][r]);
                    const float cn = fg * creg[p][r] + ig * gg;
                    creg[p][r] = cn;
                    const float hn = og * tanh_(cn);
                    Zn[m * ZSTR + 64 + jj] = (__bf16)hn;
                    CBb[m * CSTR + jj]     = (__bf16)cn;
                }
            }
        }

        __syncthreads();   // barrier B: CB ready

        if (w < 4) {
            // y_t = c_new @ W_dense^T + b_dense; dense W re-read from L2 each step
            // (laundered so it can't become a resident class).
            const __bf16* wdp = wdbase;
            asm volatile("" : "+v"(wdp));
            f32x4 ya = {ybias, ybias, ybias, ybias};
#pragma unroll
            for (int c = 0; c < 8; ++c) {
                bf16x8 wdc = *(const bf16x8*)(wdp + c * 512);
                bf16x8 acb = *(const bf16x8*)(&CBb[lr * CSTR + c * 32 + lg * 8]);
                ya = __builtin_amdgcn_mfma_f32_16x16x32_bf16(acb, wdc, ya, 0, 0, 0);
            }
            const int f = w * 16 + lr;
#pragma unroll
            for (int r = 0; r < 4; ++r) {
                const int m = lg * 4 + r;
                outp[(size_t)m * (SEQ * FD) + t * FD + f] = ya[r];  // fp32 output
                Zn[m * ZSTR + f] = (__bf16)ya[r];                   // x for next step
            }
        }
    }
}

extern "C" void kernel_launch(void* const* d_in, const int* in_sizes, int n_in,
                              void* d_out, int out_size, void* d_ws, size_t ws_size,
                              hipStream_t stream) {
    (void)in_sizes; (void)n_in; (void)ws_size; (void)out_size;
    const float* h0      = (const float*)d_in[1];
    const float* c0      = (const float*)d_in[2];
    const float* W_ih    = (const float*)d_in[3];
    const float* W_hh    = (const float*)d_in[4];
    const float* b_ih    = (const float*)d_in[5];
    const float* b_hh    = (const float*)d_in[6];
    const float* W_dense = (const float*)d_in[7];
    const float* b_dense = (const float*)d_in[8];
    __bf16* wsb = (__bf16*)d_ws;    // uses 688,128 bytes of workspace

    prep_weights<<<132, 64, 0, stream>>>(W_ih, W_hh, W_dense, wsb);
    lstm_persist<<<128, 512, 0, stream>>>(h0, c0, b_ih, b_hh, b_dense, wsb, (float*)d_out);
}

// Round 12
// 3291.117 us; speedup vs baseline: 1.1608x; 1.1608x over previous
//
#include <hip/hip_runtime.h>
#include <stdint.h>

// Problem constants: B=2048, S=512, F=64, H=256
#define SEQ   512
#define FD    64
#define HD    256
#define ZSTR  324            // bf16 elems per Z row; 162 words % 8 == 2 (conflict-free b128, <=2-way scalar writes)
#define CSTR  260            // 130 words % 8 == 2

// ws layout (prep writes, main reads): 8 wave-roles w (two 16-col j-slices each).
// Per role: 16 groups (p=i>>3, h=(i>>2)&1, nt=i&3) x 5 chunks x 1KB, consumption order.
// Chunk = 64 lanes x 16B, exact B-fragment order: lane l holds
//   W[n = nt*256 + (2w+p)*16 + (l&15)][k = h*160 + c*32 + (l>>4)*8 + e], e=0..7.
// Dense W at DENSE_OFF: 4 roles x 8 chunks x 1KB.
#define GRPB      5120
#define WGB       (16 * GRPB)        // 81,920 B per wave-role
#define DENSE_OFF (8 * WGB)          // 655,360 B

typedef __attribute__((ext_vector_type(8))) __bf16 bf16x8;
typedef __attribute__((ext_vector_type(4))) float  f32x4;

__device__ __forceinline__ float sigm(float x) {
    return __builtin_amdgcn_rcpf(1.0f + __expf(-x));
}
__device__ __forceinline__ float tanh_(float x) {
    return 2.0f * __builtin_amdgcn_rcpf(1.0f + __expf(-2.0f * x)) - 1.0f;
}

// Pinned global load: volatile asm -> cannot be sunk/hoisted/remat'd (R3-R10: hipcc
// defeats every source-level pipelining attempt). Only the LOAD is asm; math is not.
__device__ __forceinline__ void gload(bf16x8& dst, const __bf16* p) {
    asm volatile("global_load_dwordx4 %0, %1, off" : "=v"(dst) : "v"(p));
}

// Wait until buffer B's 5 loads have landed (CNT = loads still allowed in flight).
// B's values are in-out operands: every MFMA consuming B is data-dependent on this
// asm -> cannot be scheduled above the wait. MFMAs themselves stay BUILTIN so the
// compiler's MFMA hazard recognizer works (R11: asm MFMA hid the opcode -> missing
// mandatory nops between mfma write and accumulator read -> garbage).
#define WAITBUF(B, CNT) do {                                                        \
    asm volatile("s_waitcnt vmcnt(" CNT ")"                                         \
        : "+v"((B)[0]), "+v"((B)[1]), "+v"((B)[2]), "+v"((B)[3]), "+v"((B)[4])      \
        :: "memory");                                                               \
    __builtin_amdgcn_sched_barrier(0);                                              \
} while (0)

// ---------------- prep: fp32 weights -> bf16 fragment chunks in ws ----------------
__global__ __launch_bounds__(64) void prep_weights(
    const float* __restrict__ W_ih, const float* __restrict__ W_hh,
    const float* __restrict__ W_dense, __bf16* __restrict__ wsb)
{
    const int b = blockIdx.x, l = threadIdx.x, lr = l & 15, lg = l >> 4;
    if (b < 128) {
        const int w = b >> 4, i = b & 15;
        const int s = 2 * w + (i >> 3), h = (i >> 2) & 1, nt = i & 3;
        const int n = nt * 256 + s * 16 + lr;
        for (int c = 0; c < 5; ++c) {
            const int k0 = h * 160 + c * 32 + lg * 8;
            const float* src = (k0 < 64) ? (W_ih + n * 64 + k0)
                                         : (W_hh + n * 256 + (k0 - 64));
            bf16x8 v;
            for (int e = 0; e < 8; ++e) v[e] = (__bf16)src[e];
            *(bf16x8*)(wsb + (size_t)((w * 16 + i) * 5 + c) * 512 + l * 8) = v;
        }
    } else {
        const int d = b - 128;          // dense role 0..3
        const int f = d * 16 + lr;
        for (int c = 0; c < 8; ++c) {
            const float* src = W_dense + f * 256 + c * 32 + lg * 8;
            bf16x8 v;
            for (int e = 0; e < 8; ++e) v[e] = (__bf16)src[e];
            *(bf16x8*)(wsb + DENSE_OFF / 2 + d * 4096 + c * 512 + l * 8) = v;
        }
    }
}

// ---------------- main persistent LSTM kernel ----------------
// 128 blocks x 512 threads (8 waves, 2/SIMD). Weight stream (16 groups/wave/step,
// L2-resident) pipelined with an asm-pinned LOAD/WAIT skeleton: 3-buffer ring, 2
// groups (10 dwordx4) in flight, counted vmcnt. Compute (MFMA builtin, elementwise)
// floats between the pins under normal compiler scheduling/hazard handling.
// Ledger soundness: between barrier A and the "0" wait, the asm loads are the only
// vmem ops (A-frags/state = DS, elementwise = VALU, dense phase after the drain);
// pressure ~123 VGPR < 128 budget so no scratch spills enter the window.
__global__ __launch_bounds__(512) __attribute__((amdgpu_waves_per_eu(2, 2)))
void lstm_persist(
    const float* __restrict__ h0, const float* __restrict__ c0,
    const float* __restrict__ b_ih, const float* __restrict__ b_hh,
    const float* __restrict__ b_dense, const __bf16* __restrict__ wsb,
    float* __restrict__ out)
{
    __shared__ __align__(16) __bf16 Zb[2 * 16 * ZSTR];   // 20,736 B
    __shared__ __align__(16) __bf16 CBb[16 * CSTR];      //  8,320 B

    const int tid = threadIdx.x;
    const int w   = tid >> 6;       // wave 0..7: j-slices {2w, 2w+1}
    const int l   = tid & 63;
    const int lr  = l & 15;
    const int lg  = l >> 4;
    const int row0 = blockIdx.x * 16;

    const __bf16* wgbase = wsb + (size_t)w * (WGB / 2);              // this wave's 16 groups
    const __bf16* wdbase = wsb + DENSE_OFF / 2 + w * 4096 + l * 8;   // dense chunks (w<4)

    // ---- biases, initial state (two slices per wave) ----
    float biasv[2][4];
    float creg[2][4];
#pragma unroll
    for (int p = 0; p < 2; ++p) {
        const int jj = (2 * w + p) * 16 + lr;
#pragma unroll
        for (int nt = 0; nt < 4; ++nt) {
            const int n = nt * 256 + jj;
            biasv[p][nt] = b_ih[n] + b_hh[n];
        }
#pragma unroll
        for (int r = 0; r < 4; ++r)
            creg[p][r] = c0[(size_t)(row0 + lg * 4 + r) * HD + jj];
    }
    float ybias = (w < 4) ? b_dense[w * 16 + lr] : 0.0f;

    // ---- stage h0 into Z0 h-part (512 threads x 8 elems) ----
    {
        const int e0 = tid * 8;
        const int m  = e0 >> 8;
        const int j8 = e0 & 255;
        const float4 h1 = *(const float4*)(h0 + (size_t)(row0 + m) * HD + j8);
        const float4 h2 = *(const float4*)(h0 + (size_t)(row0 + m) * HD + j8 + 4);
        __bf16* zp = &Zb[m * ZSTR + 64 + j8];
        zp[0] = (__bf16)h1.x; zp[1] = (__bf16)h1.y; zp[2] = (__bf16)h1.z; zp[3] = (__bf16)h1.w;
        zp[4] = (__bf16)h2.x; zp[5] = (__bf16)h2.y; zp[6] = (__bf16)h2.z; zp[7] = (__bf16)h2.w;
    }
    __syncthreads();

    // ---- x_0 = dense(h0) -> Z0 x-part ----
    if (w < 4) {
        f32x4 ya = {ybias, ybias, ybias, ybias};
#pragma unroll
        for (int c = 0; c < 8; ++c) {
            bf16x8 wdc = *(const bf16x8*)(wdbase + c * 512);
            bf16x8 av  = *(const bf16x8*)(&Zb[lr * ZSTR + 64 + c * 32 + lg * 8]);
            ya = __builtin_amdgcn_mfma_f32_16x16x32_bf16(av, wdc, ya, 0, 0, 0);
        }
#pragma unroll
        for (int r = 0; r < 4; ++r)
            Zb[(lg * 4 + r) * ZSTR + w * 16 + lr] = (__bf16)ya[r];
    }

    float* outp = out + (size_t)row0 * SEQ * FD;

    // ---------------- 512-step recurrence ----------------
    for (int t = 0; t < SEQ; ++t) {
        __syncthreads();   // barrier A: Z[cur] complete; compiler drains vmcnt -> ledger = 0

        const __bf16* Zc = Zb + (t & 1) * (16 * ZSTR);
        __bf16*       Zn = Zb + ((t + 1) & 1) * (16 * ZSTR);

        // per-lane base; laundered so per-step addresses are recomputed, not kept live
        const __bf16* gp = wgbase + l * 8;
        asm volatile("" : "+v"(gp));

        bf16x8 R0[5], R1[5], R2[5];   // 3-slot ring, 2 groups in flight
        bf16x8 aph[5];                // A-frags for current k-half
        f32x4  acc[4];

        // prologue: issue groups 0,1
#pragma unroll
        for (int c = 0; c < 5; ++c) gload(R0[c], gp + c * 512);
#pragma unroll
        for (int c = 0; c < 5; ++c) gload(R1[c], gp + 2560 + c * 512);

#define APH_LOAD(H) {                                                              \
    _Pragma("unroll")                                                              \
    for (int c = 0; c < 5; ++c)                                                    \
        aph[c] = *(const bf16x8*)(&Zc[lr * ZSTR + ((H) * 5 + c) * 32 + lg * 8]); }

#define ISSUE(G, B) {                                                              \
    _Pragma("unroll")                                                              \
    for (int c = 0; c < 5; ++c) gload(B[c], gp + (G) * 2560 + c * 512); }

#define ELEM(P) {                                                                  \
    const int jj = (2 * w + (P)) * 16 + lr;                                        \
    _Pragma("unroll")                                                              \
    for (int r = 0; r < 4; ++r) {                                                  \
        const int m = lg * 4 + r;                                                  \
        const float ig = sigm(acc[0][r]);                                          \
        const float fg = sigm(acc[1][r]);                                          \
        const float gg = tanh_(acc[2][r]);                                         \
        const float og = sigm(acc[3][r]);                                          \
        const float cn = fg * creg[(P)][r] + ig * gg;                              \
        creg[(P)][r] = cn;                                                         \
        const float hn = og * tanh_(cn);                                           \
        Zn[m * ZSTR + 64 + jj] = (__bf16)hn;                                       \
        CBb[m * CSTR + jj]     = (__bf16)cn;                                       \
    } }

        // GSTEP(I, BCUR, BNXT, CNT): [aph reload] -> issue I+2 -> wait I -> 5 MFMA (builtin)
#define GSTEP(I, BCUR, BNXT, CNT) {                                                \
    if (((I) & 3) == 0) APH_LOAD(((I) >> 2) & 1)                                   \
    if ((I) + 2 < 16)   ISSUE((I) + 2, BNXT)                                       \
    WAITBUF(BCUR, CNT);                                                            \
    f32x4 cc;                                                                      \
    if ((((I) >> 2) & 1) == 0) {                                                   \
        const float bb = biasv[(I) >> 3][(I) & 3];                                 \
        cc = f32x4{bb, bb, bb, bb};                                                \
    } else {                                                                       \
        cc = acc[(I) & 3];                                                         \
    }                                                                              \
    cc = __builtin_amdgcn_mfma_f32_16x16x32_bf16(aph[0], BCUR[0], cc, 0, 0, 0);    \
    cc = __builtin_amdgcn_mfma_f32_16x16x32_bf16(aph[1], BCUR[1], cc, 0, 0, 0);    \
    cc = __builtin_amdgcn_mfma_f32_16x16x32_bf16(aph[2], BCUR[2], cc, 0, 0, 0);    \
    cc = __builtin_amdgcn_mfma_f32_16x16x32_bf16(aph[3], BCUR[3], cc, 0, 0, 0);    \
    cc = __builtin_amdgcn_mfma_f32_16x16x32_bf16(aph[4], BCUR[4], cc, 0, 0, 0);    \
    acc[(I) & 3] = cc; }

        GSTEP(0,  R0, R2, "10")
        GSTEP(1,  R1, R0, "10")
        GSTEP(2,  R2, R1, "10")
        GSTEP(3,  R0, R2, "10")
        GSTEP(4,  R1, R0, "10")
        GSTEP(5,  R2, R1, "10")
        GSTEP(6,  R0, R2, "10")
        GSTEP(7,  R1, R0, "10")
        ELEM(0)
        GSTEP(8,  R2, R1, "10")
        GSTEP(9,  R0, R2, "10")
        GSTEP(10, R1, R0, "10")
        GSTEP(11, R2, R1, "10")
        GSTEP(12, R0, R2, "10")
        GSTEP(13, R1, R0, "10")
        GSTEP(14, R2, R1, "5")
        GSTEP(15, R0, R2, "0")
        ELEM(1)

#undef GSTEP
#undef ELEM
#undef ISSUE
#undef APH_LOAD

        __syncthreads();   // barrier B: CB ready

        if (w < 4) {
            // y_t = c_new @ W_dense^T + b_dense; dense W re-read from L2 each step
            const __bf16* wdp = wdbase;
            asm volatile("" : "+v"(wdp));
            f32x4 ya = {ybias, ybias, ybias, ybias};
#pragma unroll
            for (int c = 0; c < 8; ++c) {
                bf16x8 wdc = *(const bf16x8*)(wdp + c * 512);
                bf16x8 acb = *(const bf16x8*)(&CBb[lr * CSTR + c * 32 + lg * 8]);
                ya = __builtin_amdgcn_mfma_f32_16x16x32_bf16(acb, wdc, ya, 0, 0, 0);
            }
            const int f = w * 16 + lr;
#pragma unroll
            for (int r = 0; r < 4; ++r) {
                const int m = lg * 4 + r;
                outp[(size_t)m * (SEQ * FD) + t * FD + f] = ya[r];  // fp32 output
                Zn[m * ZSTR + f] = (__bf16)ya[r];                   // x for next step
            }
        }
    }
}

extern "C" void kernel_launch(void* const* d_in, const int* in_sizes, int n_in,
                              void* d_out, int out_size, void* d_ws, size_t ws_size,
                              hipStream_t stream) {
    (void)in_sizes; (void)n_in; (void)ws_size; (void)out_size;
    const float* h0      = (const float*)d_in[1];
    const float* c0      = (const float*)d_in[2];
    const float* W_ih    = (const float*)d_in[3];
    const float* W_hh    = (const float*)d_in[4];
    const float* b_ih    = (const float*)d_in[5];
    const float* b_hh    = (const float*)d_in[6];
    const float* W_dense = (const float*)d_in[7];
    const float* b_dense = (const float*)d_in[8];
    __bf16* wsb = (__bf16*)d_ws;    // uses 688,128 bytes of workspace

    prep_weights<<<132, 64, 0, stream>>>(W_ih, W_hh, W_dense, wsb);
    lstm_persist<<<128, 512, 0, stream>>>(h0, c0, b_ih, b_hh, b_dense, wsb, (float*)d_out);
}